// Round 11
// baseline (658.205 us; speedup 1.0000x reference)
//
#include <hip/hip_runtime.h>
#include <hip/hip_bf16.h>

#define NN     50000
#define NN2    100000
#define NEDGE  1600000
#define NE2    3200000
#define NG     512
#define FIN    128
#define FHID   128
#define FPROJ  256

// merged radix CSR build params — 512-node coarse buckets
#define BSH    9
#define BSZ    512
#define NBUCK  98
#define NBUCK2 196
#define EPB    8192
#define NABLK  196
#define NABLK2 392
#define NHIST2 (NBUCK2*NABLK2)   // 76,832
#define NSB1   ((NHIST2 + 255) / 256)   // 301 scan blocks

// k_csr fine sort key: (fine_dst << 4) | (src >> SRCSH); neutral perf, kept.
#define SRCSH  12
#define NKEY   (BSZ * 16)        // 8192

// k_agg LDS index staging: 16 nodes/block, Poisson(32) degrees -> ~512 entries,
// 2048 covers 68 sigma. Pad +16 for pipeline prefetch overread (values unused).
#define MAXE_BLK 2048

typedef __attribute__((ext_vector_type(8))) short short8;
typedef __attribute__((ext_vector_type(4))) float f32x4;
typedef __attribute__((ext_vector_type(2))) float f32x2;

static __device__ __forceinline__ short f2bf(float f) {
    union { float f; unsigned u; } x; x.f = f;
    unsigned r = (x.u + 0x7FFFu + ((x.u >> 16) & 1u)) >> 16;
    return (short)(r & 0xFFFFu);
}
static __device__ __forceinline__ float bf2f(unsigned short u) {
    union { unsigned u; float f; } x; x.u = ((unsigned)u) << 16;
    return x.f;
}
static __device__ __forceinline__ float bflo(unsigned u) {
    union { unsigned u; float f; } x; x.u = u << 16; return x.f;
}
static __device__ __forceinline__ float bfhi(unsigned u) {
    union { unsigned u; float f; } x; x.u = u & 0xFFFF0000u; return x.f;
}
static __device__ __forceinline__ unsigned packbf(float a, float b) {
    return (unsigned)(unsigned short)f2bf(a) | ((unsigned)(unsigned short)f2bf(b) << 16);
}
// {lo,hi} bf16 pair of one dword as f32x2 -> 2 bit-ops + 1 v_pk_add_f32 on use
static __device__ __forceinline__ f32x2 bfpair(unsigned u) {
    union { unsigned v[2]; f32x2 f; } x;
    x.v[0] = u << 16;
    x.v[1] = u & 0xFFFF0000u;
    return x.f;
}

// ---------------- merged CSR build (both graphs, atomic-free at device scope) ----
// Blocks [0, NABLK2): edge histogram. Blocks [NABLK2, NABLK2+6): fused k_prepw
// (bf16 weight fragment prep) + head-stats zeroing (first prep block).

__global__ __launch_bounds__(1024) void k_bhist(const int* __restrict__ dst0,
                                                const int* __restrict__ dst1,
                                                int* __restrict__ histG,
                                                unsigned short* __restrict__ lrank,
                                                const float* __restrict__ W0,
                                                const float* __restrict__ W1,
                                                const float* __restrict__ W2,
                                                short* __restrict__ Wf,
                                                float* __restrict__ stats) {
    if (blockIdx.x >= NABLK2) {
        if (blockIdx.x == NABLK2) {        // zero head BN stats (2048 floats)
            stats[threadIdx.x] = 0.f;
            stats[threadIdx.x + 1024] = 0.f;
        }
        int w = (blockIdx.x - NABLK2) * 1024 + threadIdx.x;   // 0..6143
        int l = w >> 11;                  // layer 0..2 (2048 items each)
        int t = w & 2047;
        int b = t >> 6;                   // tile 0..31
        int lane = t & 63;
        const float* W = (l == 0) ? W0 : (l == 1) ? W1 : W2;
        int nt = b >> 2, kt = b & 3;
        int n = nt * 16 + (lane & 15);
        int kbase = kt * 32 + (lane >> 4) * 8;
        short8 v;
#pragma unroll
        for (int j = 0; j < 8; ++j) v[j] = f2bf(W[(kbase + j) * FHID + n]);
        *(short8*)(Wf + (size_t)l * 16384 + (size_t)((nt * 4 + kt) * 64 + lane) * 8) = v;
        return;
    }
    __shared__ int h[NBUCK2];
    for (int j = threadIdx.x; j < NBUCK2; j += 1024) h[j] = 0;
    __syncthreads();
    int b = blockIdx.x;                  // 0..391
    int g = b / NABLK, blk = b % NABLK;
    const int* dst = g ? dst1 : dst0;
    int base = blk * EPB;
    int gb = g * NBUCK;
    for (int t = threadIdx.x; t < EPB; t += 1024) {
        int i = base + t;
        if (i < NEDGE)
            lrank[(size_t)g * NEDGE + i] =
                (unsigned short)atomicAdd(&h[gb + (dst[i] >> BSH)], 1);
    }
    __syncthreads();
    for (int j = threadIdx.x; j < NBUCK2; j += 1024)
        histG[(size_t)j * NABLK2 + b] = h[j];
}

// parallel scan cascade (s_add folded into consumers)
__global__ void s_scan256(const int* __restrict__ in, int* __restrict__ out,
                          int* __restrict__ bsum, int n) {
    __shared__ int s[256];
    int i = blockIdx.x * 256 + threadIdx.x;
    int v = (i < n) ? in[i] : 0;
    s[threadIdx.x] = v;
    for (int o = 1; o < 256; o <<= 1) {
        __syncthreads();
        int t = (threadIdx.x >= o) ? s[threadIdx.x - o] : 0;
        __syncthreads();
        s[threadIdx.x] += t;
    }
    __syncthreads();
    if (i < n) out[i] = s[threadIdx.x] - v;   // exclusive
    if (threadIdx.x == 255) bsum[blockIdx.x] = s[255];
}

__global__ __launch_bounds__(512) void s_scan_tail(int* __restrict__ bsum, int nb) {
    __shared__ int s[512];
    int v = (threadIdx.x < nb) ? bsum[threadIdx.x] : 0;
    s[threadIdx.x] = v;
    for (int o = 1; o < 512; o <<= 1) {
        __syncthreads();
        int t = (threadIdx.x >= o) ? s[threadIdx.x - o] : 0;
        __syncthreads();
        s[threadIdx.x] += t;
    }
    __syncthreads();
    if (threadIdx.x < nb) bsum[threadIdx.x] = s[threadIdx.x] - v;  // exclusive
}

__global__ __launch_bounds__(1024) void k_part(const int* __restrict__ src0,
                                               const int* __restrict__ dst0,
                                               const int* __restrict__ src1,
                                               const int* __restrict__ dst1,
                                               const unsigned short* __restrict__ lrank,
                                               const int* __restrict__ histS,
                                               const int* __restrict__ bsum,
                                               unsigned* __restrict__ pedge) {
    int b = blockIdx.x;
    int g = b / NABLK, blk = b % NABLK;
    const int* src = g ? src1 : src0;
    const int* dst = g ? dst1 : dst0;
    int base = blk * EPB;
    int gb = g * NBUCK;
    for (int t = threadIdx.x; t < EPB; t += 1024) {
        int i = base + t;
        if (i < NEDGE) {
            int d = dst[i];
            int idx = (gb + (d >> BSH)) * NABLK2 + b;
            int pos = histS[idx] + bsum[idx >> 8]
                      + (int)lrank[(size_t)g * NEDGE + i];
            pedge[pos] = (unsigned)src[i] | ((unsigned)(d & (BSZ - 1)) << 16);
        }
    }
}

// one block per 512-node bucket -> fine CSR (ushort srcs) + csroff + dinv.
// Counting-sort key = (fine_dst<<4) | (src>>SRCSH). 512 threads (8 waves).
__global__ __launch_bounds__(512) void k_csr(const unsigned* __restrict__ pedge,
                                             const int* __restrict__ histS,
                                             const int* __restrict__ bsumG,
                                             int* __restrict__ csroff,
                                             unsigned short* __restrict__ csrc,
                                             float* __restrict__ dinv) {
    __shared__ int cnt[NKEY];            // 32KB: counts -> exclusive offsets -> bump ptrs
    __shared__ int part[512];
    int k = blockIdx.x;                  // 0..195
    int g = k / NBUCK;
    int nl0 = (k - g * NBUCK) * BSZ;
    int i0 = k * NABLK2;
    int beg = histS[i0] + bsumG[i0 >> 8];
    int end;
    if (k == NBUCK2 - 1) end = NE2;
    else { int i1 = (k + 1) * NABLK2; end = histS[i1] + bsumG[i1 >> 8]; }
    int t = threadIdx.x;
    for (int j = t; j < NKEY; j += 512) cnt[j] = 0;
    __syncthreads();
    for (int e = beg + t; e < end; e += 512) {
        unsigned v = pedge[e];
        int key = (int)((v >> 16) << 4) | (int)((v & 0xFFFFu) >> SRCSH);
        atomicAdd(&cnt[key], 1);
    }
    __syncthreads();
    // exclusive scan over 8192: 16 serial per thread + block scan of partials
    int base = t * 16;
    int s = 0;
#pragma unroll
    for (int j = 0; j < 16; ++j) s += cnt[base + j];
    part[t] = s;
    for (int o = 1; o < 512; o <<= 1) {
        __syncthreads();
        int v2 = (t >= o) ? part[t - o] : 0;
        __syncthreads();
        part[t] += v2;
    }
    __syncthreads();
    int run = part[t] - s;               // exclusive prefix of this thread's chunk
#pragma unroll
    for (int j = 0; j < 16; ++j) { int c = cnt[base + j]; cnt[base + j] = run; run += c; }
    __syncthreads();
    // per-node degree / csroff / dinv from offset boundaries (before bump overwrites)
    {
        int nl = nl0 + t;                // 512 threads == BSZ nodes, one each
        if (nl < NN) {
            int gn = g * NN + nl;
            int d0 = cnt[t * 16];
            int d1 = (t == BSZ - 1) ? (end - beg) : cnt[(t + 1) * 16];
            csroff[gn] = beg + d0;
            dinv[gn] = 1.0f / sqrtf((float)(d1 - d0 + 1));
        }
    }
    __syncthreads();
    // placement: bump-allocate on cnt (holds exclusive offsets)
    for (int e = beg + t; e < end; e += 512) {
        unsigned v = pedge[e];
        int key = (int)((v >> 16) << 4) | (int)((v & 0xFFFFu) >> SRCSH);
        int r = atomicAdd(&cnt[key], 1);
        csrc[beg + r] = (unsigned short)(v & 0xFFFFu);
    }
    if (k == NBUCK2 - 1 && t == 0) csroff[NN2] = NE2;
}

// ---------------- MFMA GEMM over both graphs: hp[i,:] = bf16((A[i,:]@W)*dinv[i]) ----

__global__ __launch_bounds__(256) void k_gemm(const float* __restrict__ x1,
                                              const float* __restrict__ x2,
                                              const unsigned short* __restrict__ Abf,
                                              const short* __restrict__ Wf,
                                              const float* __restrict__ dinv,
                                              unsigned short* __restrict__ hp) {
    int lane = threadIdx.x & 63;
    int wv = threadIdx.x >> 6;
    int quad = lane >> 4;
    int rowbase = blockIdx.x * 64 + wv * 16;    // 1564 blocks -> 100,096 rows
    int arow = rowbase + (lane & 15);
    if (arow >= NN2) arow = NN2 - 1;

    f32x4 acc[8];
#pragma unroll
    for (int i = 0; i < 8; ++i) acc[i] = (f32x4){0.f, 0.f, 0.f, 0.f};

#pragma unroll
    for (int kt = 0; kt < 4; ++kt) {
        short8 af;
        if (Abf) {
            af = *(const short8*)(Abf + (size_t)arow * FIN + kt * 32 + quad * 8);
        } else {
            const float* ap = (arow < NN ? x1 + (size_t)arow * FIN
                                         : x2 + (size_t)(arow - NN) * FIN)
                              + kt * 32 + quad * 8;
            float4 a0 = *(const float4*)ap;
            float4 a1 = *(const float4*)(ap + 4);
            af[0] = f2bf(a0.x); af[1] = f2bf(a0.y); af[2] = f2bf(a0.z); af[3] = f2bf(a0.w);
            af[4] = f2bf(a1.x); af[5] = f2bf(a1.y); af[6] = f2bf(a1.z); af[7] = f2bf(a1.w);
        }
#pragma unroll
        for (int nt = 0; nt < 8; ++nt) {
            short8 bf = *(const short8*)(Wf + (size_t)((nt * 4 + kt) * 64 + lane) * 8);
            acc[nt] = __builtin_amdgcn_mfma_f32_16x16x32_bf16(af, bf, acc[nt], 0, 0, 0);
        }
    }
    // C/D layout: col = lane&15, row = quad*4 + reg   [measured m89/m91]
    float4 dv = *(const float4*)(dinv + rowbase + quad * 4);
    float dvv[4] = {dv.x, dv.y, dv.z, dv.w};
    int col = lane & 15;
#pragma unroll
    for (int r = 0; r < 4; ++r) {
        int orow = rowbase + quad * 4 + r;
        if (orow < NN2) {
#pragma unroll
            for (int nt = 0; nt < 8; ++nt)
                hp[(size_t)orow * FHID + nt * 16 + col] =
                    (unsigned short)f2bf(acc[nt][r] * dvv[r]);
        }
    }
}

// ------- Aggregate: 16 lanes/node, dwordx4 gathers, depth-2 x batch-4 pipeline
// with LDS-staged indices. sched_barrier(0) after each gather-issue pins the
// order so ACC of the previous batch can't be hoisted above it (r10's VGPR=44
// showed the compiler serialized the unpinned pipeline); batch-4 keeps total
// pressure ~80 VGPR so pinning can't spill (r7's batch-8 + bound,4 spilled).

#define SCHB __builtin_amdgcn_sched_barrier(0)
#define RDI(S, EE) { _Pragma("unroll") for (int j = 0; j < 4; ++j) S[j] = (int)sidx[(EE) + j]; }
#define GTH(V, S)  { _Pragma("unroll") for (int j = 0; j < 4; ++j) V[j] = hpg[(size_t)S[j] * 16 + l16]; }
#define ACC4(V)    { _Pragma("unroll") for (int j = 0; j < 4; ++j) { \
                       a0 += bfpair(V[j].x); a1 += bfpair(V[j].y);   \
                       a2 += bfpair(V[j].z); a3 += bfpair(V[j].w); } }

__global__ __launch_bounds__(256) void k_agg(const uint4* __restrict__ hp4,
                                             const int* __restrict__ off,
                                             const unsigned short* __restrict__ csrc,
                                             const float* __restrict__ dinv,
                                             const float* __restrict__ bias,
                                             const unsigned short* __restrict__ resid,
                                             unsigned short* __restrict__ hout) {
    __shared__ unsigned short sidx[MAXE_BLK + 16];
    int tid = threadIdx.x;
    int l16 = tid & 15;
    int grp = tid >> 4;                       // 16 node-groups per block
    int gnb = blockIdx.x * 16;                // 6250 blocks -> 100,000 nodes
    // stage the block's contiguous csrc range into LDS (coalesced)
    int blkBeg = off[gnb];
    int blkLen = off[gnb + 16] - blkBeg;      // off[NN2] valid (csroff has NN2+1)
    if (blkLen > MAXE_BLK) blkLen = MAXE_BLK; // 68-sigma impossible; fault-safe clamp
    for (int i = tid; i < blkLen; i += 256)
        sidx[i] = csrc[blkBeg + i];
    __syncthreads();

    int gn = gnb + grp;
    int g = gn >= NN;
    int node = gn - g * NN;
    const uint4* hpg = hp4 + (size_t)g * NN * 16;
    int beg = off[gn], end = off[gn + 1];
    int lbeg = beg - blkBeg;

    uint4 sv = hpg[(size_t)node * 16 + l16];  // self-loop row (oldest; used in epilogue)
    f32x2 a0 = (f32x2){0.f, 0.f}, a1 = (f32x2){0.f, 0.f};
    f32x2 a2 = (f32x2){0.f, 0.f}, a3 = (f32x2){0.f, 0.f};

    int n4 = (end - beg) >> 2;                // full 4-batches
    if (n4 >= 2) {
        int s0[4], s1[4];
        uint4 v0[4], v1[4];
        int e = lbeg;
        RDI(s0, e);
        RDI(s1, e + 4);
        GTH(v0, s0); SCHB;                    // batch 0 in flight
        e += 8;
        int k = 1;                            // next batch to issue
        while (k + 2 <= n4) {
            GTH(v1, s1); SCHB;                // issue batch k (v0+v1 in flight)
            RDI(s0, e); e += 4;               // LDS idx batch k+1 (lgkm, no vmcnt)
            ACC4(v0);                         // counted vmcnt; batch k stays in flight
            GTH(v0, s0); SCHB;                // issue batch k+1
            RDI(s1, e); e += 4;               // LDS idx batch k+2 (pad-safe)
            ACC4(v1);
            k += 2;
        }
        if (k < n4) {                         // one more full batch (k == n4-1)
            GTH(v1, s1); SCHB;
            ACC4(v0);
            ACC4(v1);
        } else {
            ACC4(v0);
        }
    } else if (n4 == 1) {
        int s0[4]; uint4 v0[4];
        RDI(s0, lbeg);
        GTH(v0, s0);
        ACC4(v0);
    }
    // tail (<4 edges) from LDS indices
    int et = lbeg + (n4 << 2), lend = lbeg + (end - beg);
    for (; et < lend; ++et) {
        uint4 w = hpg[(size_t)sidx[et] * 16 + l16];
        a0 += bfpair(w.x); a1 += bfpair(w.y); a2 += bfpair(w.z); a3 += bfpair(w.w);
    }
    // self-loop contribution (sv issued at kernel start)
    a0 += bfpair(sv.x); a1 += bfpair(sv.y); a2 += bfpair(sv.z); a3 += bfpair(sv.w);

    float dv = dinv[gn];
    float4 b0 = ((const float4*)bias)[l16 * 2];
    float4 b1 = ((const float4*)bias)[l16 * 2 + 1];
    float o0 = fmaxf(a0.x * dv + b0.x, 0.f);
    float o1 = fmaxf(a0.y * dv + b0.y, 0.f);
    float o2 = fmaxf(a1.x * dv + b0.z, 0.f);
    float o3 = fmaxf(a1.y * dv + b0.w, 0.f);
    float o4 = fmaxf(a2.x * dv + b1.x, 0.f);
    float o5 = fmaxf(a2.y * dv + b1.y, 0.f);
    float o6 = fmaxf(a3.x * dv + b1.z, 0.f);
    float o7 = fmaxf(a3.y * dv + b1.w, 0.f);
    if (resid) {
        uint4 rv = ((const uint4*)resid)[(size_t)gn * 16 + l16];
        o0 += bflo(rv.x); o1 += bfhi(rv.x);
        o2 += bflo(rv.y); o3 += bfhi(rv.y);
        o4 += bflo(rv.z); o5 += bfhi(rv.z);
        o6 += bflo(rv.w); o7 += bfhi(rv.w);
    }
    uint4 ov;
    ov.x = packbf(o0, o1);
    ov.y = packbf(o2, o3);
    ov.z = packbf(o4, o5);
    ov.w = packbf(o6, o7);
    ((uint4*)hout)[(size_t)gn * 16 + l16] = ov;
}

// ---------------- Pooling + head1 fused (4 graphs/block, both graphs-of-pair) ----

static __device__ __forceinline__ int lbound(const int* __restrict__ a, int key) {
    int lo = 0, hi = NN;
    while (lo < hi) { int mid = (lo + hi) >> 1; if (a[mid] < key) lo = mid + 1; else hi = mid; }
    return lo;
}

// k_head_pool: mean-pool 4 graphs' node rows (bf16 h_cur) into LDS, then the
// K=128 -> NC=256 GEMM with column-parallel threads and x8-unrolled K loop.
__global__ __launch_bounds__(256) void k_head_pool(const unsigned short* __restrict__ h,
                                                   const int* __restrict__ b0,
                                                   const int* __restrict__ b1,
                                                   const float* __restrict__ W,
                                                   const float* __restrict__ bias,
                                                   float* __restrict__ out,
                                                   float* __restrict__ statsOut) {
    __shared__ float As[4 * 128];
    __shared__ int bnds[5];
    int t = threadIdx.x;
    int r0 = blockIdx.x * 4;              // 256 blocks -> 1024 rows; 512%4==0 so no g-straddle
    int g = (r0 >= NG) ? 1 : 0;
    int lg0 = r0 & (NG - 1);
    const int* batch = g ? b1 : b0;
    if (t < 5) bnds[t] = lbound(batch, lg0 + t);
    __syncthreads();
    {
        int c = t & 127, half = t >> 7;
        const unsigned short* hb = h + (size_t)g * NN * FHID;
        for (int rr = 0; rr < 2; ++rr) {
            int r = half * 2 + rr;
            int beg = bnds[r], end = bnds[r + 1];
            float s = 0.f;
            for (int i = beg; i < end; ++i) s += bf2f(hb[(size_t)i * FHID + c]);
            int cnt = end - beg;
            As[r * 128 + c] = s / (float)(cnt > 0 ? cnt : 1);
        }
    }
    __syncthreads();
    float bb = bias[t];
    float acc[4] = {bb, bb, bb, bb};
    for (int k = 0; k < 128; k += 8) {
        float w0 = W[(size_t)(k + 0) * 256 + t];
        float w1 = W[(size_t)(k + 1) * 256 + t];
        float w2 = W[(size_t)(k + 2) * 256 + t];
        float w3 = W[(size_t)(k + 3) * 256 + t];
        float w4 = W[(size_t)(k + 4) * 256 + t];
        float w5 = W[(size_t)(k + 5) * 256 + t];
        float w6 = W[(size_t)(k + 6) * 256 + t];
        float w7 = W[(size_t)(k + 7) * 256 + t];
#pragma unroll
        for (int r = 0; r < 4; ++r) {
            float4 q0 = *(const float4*)(As + r * 128 + k);
            float4 q1 = *(const float4*)(As + r * 128 + k + 4);
            acc[r] = fmaf(q0.x, w0, acc[r]);
            acc[r] = fmaf(q0.y, w1, acc[r]);
            acc[r] = fmaf(q0.z, w2, acc[r]);
            acc[r] = fmaf(q0.w, w3, acc[r]);
            acc[r] = fmaf(q1.x, w4, acc[r]);
            acc[r] = fmaf(q1.y, w5, acc[r]);
            acc[r] = fmaf(q1.z, w6, acc[r]);
            acc[r] = fmaf(q1.w, w7, acc[r]);
        }
    }
    {
        float s = 0.f, q = 0.f;
#pragma unroll
        for (int r = 0; r < 4; ++r) { s += acc[r]; q += acc[r] * acc[r]; }
        atomicAdd(&statsOut[g * 512 + t], s);
        atomicAdd(&statsOut[g * 512 + 256 + t], q);
    }
#pragma unroll
    for (int r = 0; r < 4; ++r)
        out[(size_t)(r0 + r) * 256 + t] = acc[r];
}

// ---------------- Head GEMMs (1024 rows = both graphs) ----------------
// k_head<NC>: 256 blocks x 256 threads, 4 rows/block. Thread owns one output
// column (coalesced W[k][c] loads), K-loop unrolled x8, As staged in LDS,
// compile-time trip counts. statsIn applies BN input transform (bnRelu:
// relu(BN) vs BN); zout stores transformed input rows; statsOut accumulates
// column sum/sumsq.

template<int NC>
__global__ __launch_bounds__(256) void k_head(const float* __restrict__ A,
                                              const float* __restrict__ W,
                                              const float* __restrict__ bias,
                                              float* __restrict__ out,
                                              int K, int act,
                                              float* __restrict__ statsOut,
                                              const float* __restrict__ statsIn,
                                              const float* __restrict__ gIn,
                                              const float* __restrict__ beIn,
                                              int bnRelu, float* __restrict__ zout) {
    constexpr int NGRP = 256 / NC;        // 1 (NC=256) or 2 (NC=128)
    constexpr int RPG  = 4 / NGRP;        // 4 or 2 rows per thread
    __shared__ float As[4 * 256];         // 4 rows x K (K <= 256)
    __shared__ float scl[256], shf[256];
    int t = threadIdx.x;
    int c = t & (NC - 1);
    int rg = t / NC;                      // 0 .. NGRP-1
    int r0 = blockIdx.x * 4;              // 256 blocks -> 1024 rows
    int g = (r0 >= NG) ? 1 : 0;
    if (statsIn) {
        const float* si = statsIn + g * 512;
        for (int j = t; j < K; j += 256) {
            float m = si[j] * (1.f / 512.f);
            float var = si[K + j] * (1.f / 512.f) - m * m;
            float inv = 1.0f / sqrtf(var + 1e-5f);
            float s = gIn[j] * inv;
            scl[j] = s;
            shf[j] = beIn[j] - m * s;
        }
    }
    __syncthreads();
    for (int idx = t; idx < 4 * K; idx += 256) {
        float v = A[(size_t)r0 * K + idx];
        if (statsIn) {
            int k = idx & (K - 1);        // K is 128 or 256
            v = v * scl[k] + shf[k];
            if (bnRelu) v = fmaxf(v, 0.f);
        }
        if (zout) zout[(size_t)r0 * K + idx] = v;
        As[idx] = v;
    }
    __syncthreads();
    float bb = bias[c];
    float acc[RPG];
#pragma unroll
    for (int r = 0; r < RPG; ++r) acc[r] = bb;
    const float* Ab = As + (rg * RPG) * K;
    for (int k = 0; k < K; k += 8) {      // K % 8 == 0
        float w0 = W[(size_t)(k + 0) * NC + c];
        float w1 = W[(size_t)(k + 1) * NC + c];
        float w2 = W[(size_t)(k + 2) * NC + c];
        float w3 = W[(size_t)(k + 3) * NC + c];
        float w4 = W[(size_t)(k + 4) * NC + c];
        float w5 = W[(size_t)(k + 5) * NC + c];
        float w6 = W[(size_t)(k + 6) * NC + c];
        float w7 = W[(size_t)(k + 7) * NC + c];
#pragma unroll
        for (int r = 0; r < RPG; ++r) {
            float4 a0 = *(const float4*)(Ab + r * K + k);
            float4 a1 = *(const float4*)(Ab + r * K + k + 4);
            acc[r] = fmaf(a0.x, w0, acc[r]);
            acc[r] = fmaf(a0.y, w1, acc[r]);
            acc[r] = fmaf(a0.z, w2, acc[r]);
            acc[r] = fmaf(a0.w, w3, acc[r]);
            acc[r] = fmaf(a1.x, w4, acc[r]);
            acc[r] = fmaf(a1.y, w5, acc[r]);
            acc[r] = fmaf(a1.z, w6, acc[r]);
            acc[r] = fmaf(a1.w, w7, acc[r]);
        }
    }
    if (statsOut) {                       // used only by NC=256 heads
        float s = 0.f, q = 0.f;
#pragma unroll
        for (int r = 0; r < RPG; ++r) { s += acc[r]; q += acc[r] * acc[r]; }
        atomicAdd(&statsOut[g * 512 + c], s);
        atomicAdd(&statsOut[g * 512 + NC + c], q);
    }
#pragma unroll
    for (int r = 0; r < RPG; ++r) {
        float v = acc[r];
        if (act) v = fmaxf(v, 0.f);
        out[(size_t)(r0 + rg * RPG + r) * NC + c] = v;
    }
}

// ---------------- Orchestration ----------------

extern "C" void kernel_launch(void* const* d_in, const int* in_sizes, int n_in,
                              void* d_out, int out_size, void* d_ws, size_t ws_size,
                              hipStream_t stream) {
    const float* x1 = (const float*)d_in[0];
    const float* x2 = (const float*)d_in[3];
    const int*   ei[2]    = {(const int*)d_in[1], (const int*)d_in[4]};
    const int*   batch[2] = {(const int*)d_in[2], (const int*)d_in[5]};
    const float* W[3]  = {(const float*)d_in[6], (const float*)d_in[8], (const float*)d_in[10]};
    const float* bb[3] = {(const float*)d_in[7], (const float*)d_in[9], (const float*)d_in[11]};
    const float* Wp1 = (const float*)d_in[12]; const float* bp1 = (const float*)d_in[13];
    const float* g1  = (const float*)d_in[14]; const float* be1 = (const float*)d_in[15];
    const float* Wp2 = (const float*)d_in[16]; const float* bp2 = (const float*)d_in[17];
    const float* g2  = (const float*)d_in[18]; const float* be2 = (const float*)d_in[19];
    const float* Wq1 = (const float*)d_in[20]; const float* bq1 = (const float*)d_in[21];
    const float* Wq2 = (const float*)d_in[22]; const float* bq2 = (const float*)d_in[23];

    char* ws = (char*)d_ws;
    size_t off = 0;
    auto alloc = [&](size_t bytes) -> void* {
        void* p = ws + off;
        off += (bytes + 255) & ~(size_t)255;
        return p;
    };
    unsigned short* h_cur  = (unsigned short*)alloc((size_t)NN2 * FHID * 2);  // bf16 state
    unsigned short* hp     = (unsigned short*)alloc((size_t)NN2 * FHID * 2);  // bf16 pre-agg
    unsigned short* csrc   = (unsigned short*)alloc((size_t)(NE2 + 16) * 2);  // +16 pad
    int*            csroff = (int*)alloc((size_t)(NN2 + 1) * 4);
    unsigned short* lrank  = (unsigned short*)alloc((size_t)NE2 * 2);
    unsigned*       pedge  = (unsigned*)alloc((size_t)NE2 * 4);
    int*            histG  = (int*)alloc((size_t)NHIST2 * 4);
    int*            histS  = (int*)alloc((size_t)NHIST2 * 4);
    int*            bsum   = (int*)alloc(512 * 4);
    float*          dinv   = (float*)alloc((size_t)100352 * 4);  // padded for gemm epilogue
    short*          Wf     = (short*)alloc((size_t)3 * 16384 * 2);
    float*          t1     = (float*)alloc((size_t)1024 * 256 * 4);
    float*          t2     = (float*)alloc((size_t)1024 * 256 * 4);
    float*          t3     = (float*)alloc((size_t)1024 * 128 * 4);
    float*          stats  = (float*)alloc(2048 * 4);  // [st1: 2g x 512][st2: 2g x 512]

    const int* src0 = ei[0];           const int* dst0 = ei[0] + NEDGE;
    const int* src1 = ei[1];           const int* dst1 = ei[1] + NEDGE;

    // merged atomic-free radix CSR build + fused weight prep + stats zero
    k_bhist<<<NABLK2 + 6, 1024, 0, stream>>>(dst0, dst1, histG, lrank,
                                             W[0], W[1], W[2], Wf, stats);
    s_scan256<<<NSB1, 256, 0, stream>>>(histG, histS, bsum, NHIST2);
    s_scan_tail<<<1, 512, 0, stream>>>(bsum, NSB1);
    k_part<<<NABLK2, 1024, 0, stream>>>(src0, dst0, src1, dst1, lrank, histS,
                                        bsum, pedge);
    k_csr<<<NBUCK2, 512, 0, stream>>>(pedge, histS, bsum, csroff, csrc, dinv);

    // encoder: merged gemm, merged two-graph aggregation (LDS-idx pipelined gathers)
    for (int l = 0; l < 3; ++l) {
        const unsigned short* Abf = (l == 0) ? nullptr : h_cur;
        const unsigned short* resid = (l == 0) ? nullptr : h_cur;
        k_gemm<<<1564, 256, 0, stream>>>(x1, x2, Abf, Wf + (size_t)l * 16384, dinv, hp);
        k_agg<<<6250, 256, 0, stream>>>((const uint4*)hp, csroff, csrc, dinv,
                                        bb[l], resid, h_cur);
    }

    // merged heads (1024 rows, per-graph BN stats); pool fused into head1,
    // bnapply fused into head3
    float* outp = (float*)d_out;
    float* p_out = outp;                           // p1,p2 contiguous [1024,256]
    float* z_out = outp + (size_t)2 * NG * FPROJ;  // z1,z2 contiguous [1024,256]
    float* st1 = stats, *st2 = stats + 1024;
    k_head_pool<<<256, 256, 0, stream>>>(h_cur, batch[0], batch[1],
                                         Wp1, bp1, t1, st1);
    k_head<256><<<256, 256, 0, stream>>>(t1, Wp2, bp2, t2, 256, 0,
                                         st2, st1, g1, be1, 1, nullptr);
    k_head<128><<<256, 256, 0, stream>>>(t2, Wq1, bq1, t3, 256, 1,
                                         nullptr, st2, g2, be2, 0, z_out);
    k_head<256><<<256, 256, 0, stream>>>(t3, Wq2, bq2, p_out, 128, 0,
                                         nullptr, nullptr, nullptr, nullptr, 0, nullptr);
}

// Round 12
// 633.307 us; speedup vs baseline: 1.0393x; 1.0393x over previous
//
#include <hip/hip_runtime.h>
#include <hip/hip_bf16.h>

#define NN     50000
#define NN2    100000
#define NEDGE  1600000
#define NE2    3200000
#define NG     512
#define FIN    128
#define FHID   128
#define FPROJ  256

// merged radix CSR build params — 512-node coarse buckets
#define BSH    9
#define BSZ    512
#define NBUCK  98
#define NBUCK2 196
#define EPB    8192
#define NABLK  196
#define NABLK2 392
#define NHIST2 (NBUCK2*NABLK2)   // 76,832
#define NSB1   ((NHIST2 + 255) / 256)   // 301 scan blocks

// k_csr fine sort key: (fine_dst << 4) | (src >> SRCSH); neutral perf, kept.
#define SRCSH  12
#define NKEY   (BSZ * 16)        // 8192

// k_agg LDS index staging: 16 nodes/block, Poisson(32) degrees -> ~512 entries,
// 2048 covers 68 sigma. Pad +16 for pipeline prefetch overread (values unused).
#define MAXE_BLK 2048

typedef __attribute__((ext_vector_type(8))) short short8;
typedef __attribute__((ext_vector_type(4))) float f32x4;
typedef __attribute__((ext_vector_type(2))) float f32x2;

static __device__ __forceinline__ short f2bf(float f) {
    union { float f; unsigned u; } x; x.f = f;
    unsigned r = (x.u + 0x7FFFu + ((x.u >> 16) & 1u)) >> 16;
    return (short)(r & 0xFFFFu);
}
static __device__ __forceinline__ float bf2f(unsigned short u) {
    union { unsigned u; float f; } x; x.u = ((unsigned)u) << 16;
    return x.f;
}
static __device__ __forceinline__ float bflo(unsigned u) {
    union { unsigned u; float f; } x; x.u = u << 16; return x.f;
}
static __device__ __forceinline__ float bfhi(unsigned u) {
    union { unsigned u; float f; } x; x.u = u & 0xFFFF0000u; return x.f;
}
static __device__ __forceinline__ unsigned packbf(float a, float b) {
    return (unsigned)(unsigned short)f2bf(a) | ((unsigned)(unsigned short)f2bf(b) << 16);
}
// {lo,hi} bf16 pair of one dword as f32x2 -> 2 bit-ops + 1 v_pk_add_f32 on use
static __device__ __forceinline__ f32x2 bfpair(unsigned u) {
    union { unsigned v[2]; f32x2 f; } x;
    x.v[0] = u << 16;
    x.v[1] = u & 0xFFFF0000u;
    return x.f;
}

// ---------------- merged CSR build (both graphs, atomic-free at device scope) ----
// Blocks [0, NABLK2): edge histogram. Blocks [NABLK2, NABLK2+6): fused k_prepw
// (bf16 weight fragment prep) + head-stats zeroing (first prep block).

__global__ __launch_bounds__(1024) void k_bhist(const int* __restrict__ dst0,
                                                const int* __restrict__ dst1,
                                                int* __restrict__ histG,
                                                unsigned short* __restrict__ lrank,
                                                const float* __restrict__ W0,
                                                const float* __restrict__ W1,
                                                const float* __restrict__ W2,
                                                short* __restrict__ Wf,
                                                float* __restrict__ stats) {
    if (blockIdx.x >= NABLK2) {
        if (blockIdx.x == NABLK2) {        // zero head BN stats (2048 floats)
            stats[threadIdx.x] = 0.f;
            stats[threadIdx.x + 1024] = 0.f;
        }
        int w = (blockIdx.x - NABLK2) * 1024 + threadIdx.x;   // 0..6143
        int l = w >> 11;                  // layer 0..2 (2048 items each)
        int t = w & 2047;
        int b = t >> 6;                   // tile 0..31
        int lane = t & 63;
        const float* W = (l == 0) ? W0 : (l == 1) ? W1 : W2;
        int nt = b >> 2, kt = b & 3;
        int n = nt * 16 + (lane & 15);
        int kbase = kt * 32 + (lane >> 4) * 8;
        short8 v;
#pragma unroll
        for (int j = 0; j < 8; ++j) v[j] = f2bf(W[(kbase + j) * FHID + n]);
        *(short8*)(Wf + (size_t)l * 16384 + (size_t)((nt * 4 + kt) * 64 + lane) * 8) = v;
        return;
    }
    __shared__ int h[NBUCK2];
    for (int j = threadIdx.x; j < NBUCK2; j += 1024) h[j] = 0;
    __syncthreads();
    int b = blockIdx.x;                  // 0..391
    int g = b / NABLK, blk = b % NABLK;
    const int* dst = g ? dst1 : dst0;
    int base = blk * EPB;
    int gb = g * NBUCK;
    for (int t = threadIdx.x; t < EPB; t += 1024) {
        int i = base + t;
        if (i < NEDGE)
            lrank[(size_t)g * NEDGE + i] =
                (unsigned short)atomicAdd(&h[gb + (dst[i] >> BSH)], 1);
    }
    __syncthreads();
    for (int j = threadIdx.x; j < NBUCK2; j += 1024)
        histG[(size_t)j * NABLK2 + b] = h[j];
}

// parallel scan cascade (s_add folded into consumers)
__global__ void s_scan256(const int* __restrict__ in, int* __restrict__ out,
                          int* __restrict__ bsum, int n) {
    __shared__ int s[256];
    int i = blockIdx.x * 256 + threadIdx.x;
    int v = (i < n) ? in[i] : 0;
    s[threadIdx.x] = v;
    for (int o = 1; o < 256; o <<= 1) {
        __syncthreads();
        int t = (threadIdx.x >= o) ? s[threadIdx.x - o] : 0;
        __syncthreads();
        s[threadIdx.x] += t;
    }
    __syncthreads();
    if (i < n) out[i] = s[threadIdx.x] - v;   // exclusive
    if (threadIdx.x == 255) bsum[blockIdx.x] = s[255];
}

__global__ __launch_bounds__(512) void s_scan_tail(int* __restrict__ bsum, int nb) {
    __shared__ int s[512];
    int v = (threadIdx.x < nb) ? bsum[threadIdx.x] : 0;
    s[threadIdx.x] = v;
    for (int o = 1; o < 512; o <<= 1) {
        __syncthreads();
        int t = (threadIdx.x >= o) ? s[threadIdx.x - o] : 0;
        __syncthreads();
        s[threadIdx.x] += t;
    }
    __syncthreads();
    if (threadIdx.x < nb) bsum[threadIdx.x] = s[threadIdx.x] - v;  // exclusive
}

__global__ __launch_bounds__(1024) void k_part(const int* __restrict__ src0,
                                               const int* __restrict__ dst0,
                                               const int* __restrict__ src1,
                                               const int* __restrict__ dst1,
                                               const unsigned short* __restrict__ lrank,
                                               const int* __restrict__ histS,
                                               const int* __restrict__ bsum,
                                               unsigned* __restrict__ pedge) {
    int b = blockIdx.x;
    int g = b / NABLK, blk = b % NABLK;
    const int* src = g ? src1 : src0;
    const int* dst = g ? dst1 : dst0;
    int base = blk * EPB;
    int gb = g * NBUCK;
    for (int t = threadIdx.x; t < EPB; t += 1024) {
        int i = base + t;
        if (i < NEDGE) {
            int d = dst[i];
            int idx = (gb + (d >> BSH)) * NABLK2 + b;
            int pos = histS[idx] + bsum[idx >> 8]
                      + (int)lrank[(size_t)g * NEDGE + i];
            pedge[pos] = (unsigned)src[i] | ((unsigned)(d & (BSZ - 1)) << 16);
        }
    }
}

// one block per 512-node bucket -> fine CSR (ushort srcs) + csroff + dinv.
// Counting-sort key = (fine_dst<<4) | (src>>SRCSH). 512 threads (8 waves).
__global__ __launch_bounds__(512) void k_csr(const unsigned* __restrict__ pedge,
                                             const int* __restrict__ histS,
                                             const int* __restrict__ bsumG,
                                             int* __restrict__ csroff,
                                             unsigned short* __restrict__ csrc,
                                             float* __restrict__ dinv) {
    __shared__ int cnt[NKEY];            // 32KB: counts -> exclusive offsets -> bump ptrs
    __shared__ int part[512];
    int k = blockIdx.x;                  // 0..195
    int g = k / NBUCK;
    int nl0 = (k - g * NBUCK) * BSZ;
    int i0 = k * NABLK2;
    int beg = histS[i0] + bsumG[i0 >> 8];
    int end;
    if (k == NBUCK2 - 1) end = NE2;
    else { int i1 = (k + 1) * NABLK2; end = histS[i1] + bsumG[i1 >> 8]; }
    int t = threadIdx.x;
    for (int j = t; j < NKEY; j += 512) cnt[j] = 0;
    __syncthreads();
    for (int e = beg + t; e < end; e += 512) {
        unsigned v = pedge[e];
        int key = (int)((v >> 16) << 4) | (int)((v & 0xFFFFu) >> SRCSH);
        atomicAdd(&cnt[key], 1);
    }
    __syncthreads();
    // exclusive scan over 8192: 16 serial per thread + block scan of partials
    int base = t * 16;
    int s = 0;
#pragma unroll
    for (int j = 0; j < 16; ++j) s += cnt[base + j];
    part[t] = s;
    for (int o = 1; o < 512; o <<= 1) {
        __syncthreads();
        int v2 = (t >= o) ? part[t - o] : 0;
        __syncthreads();
        part[t] += v2;
    }
    __syncthreads();
    int run = part[t] - s;               // exclusive prefix of this thread's chunk
#pragma unroll
    for (int j = 0; j < 16; ++j) { int c = cnt[base + j]; cnt[base + j] = run; run += c; }
    __syncthreads();
    // per-node degree / csroff / dinv from offset boundaries (before bump overwrites)
    {
        int nl = nl0 + t;                // 512 threads == BSZ nodes, one each
        if (nl < NN) {
            int gn = g * NN + nl;
            int d0 = cnt[t * 16];
            int d1 = (t == BSZ - 1) ? (end - beg) : cnt[(t + 1) * 16];
            csroff[gn] = beg + d0;
            dinv[gn] = 1.0f / sqrtf((float)(d1 - d0 + 1));
        }
    }
    __syncthreads();
    // placement: bump-allocate on cnt (holds exclusive offsets)
    for (int e = beg + t; e < end; e += 512) {
        unsigned v = pedge[e];
        int key = (int)((v >> 16) << 4) | (int)((v & 0xFFFFu) >> SRCSH);
        int r = atomicAdd(&cnt[key], 1);
        csrc[beg + r] = (unsigned short)(v & 0xFFFFu);
    }
    if (k == NBUCK2 - 1 && t == 0) csroff[NN2] = NE2;
}

// ---------------- MFMA GEMM over both graphs: hp[i,:] = bf16((A[i,:]@W)*dinv[i]) ----

__global__ __launch_bounds__(256) void k_gemm(const float* __restrict__ x1,
                                              const float* __restrict__ x2,
                                              const unsigned short* __restrict__ Abf,
                                              const short* __restrict__ Wf,
                                              const float* __restrict__ dinv,
                                              unsigned short* __restrict__ hp) {
    int lane = threadIdx.x & 63;
    int wv = threadIdx.x >> 6;
    int quad = lane >> 4;
    int rowbase = blockIdx.x * 64 + wv * 16;    // 1564 blocks -> 100,096 rows
    int arow = rowbase + (lane & 15);
    if (arow >= NN2) arow = NN2 - 1;

    f32x4 acc[8];
#pragma unroll
    for (int i = 0; i < 8; ++i) acc[i] = (f32x4){0.f, 0.f, 0.f, 0.f};

#pragma unroll
    for (int kt = 0; kt < 4; ++kt) {
        short8 af;
        if (Abf) {
            af = *(const short8*)(Abf + (size_t)arow * FIN + kt * 32 + quad * 8);
        } else {
            const float* ap = (arow < NN ? x1 + (size_t)arow * FIN
                                         : x2 + (size_t)(arow - NN) * FIN)
                              + kt * 32 + quad * 8;
            float4 a0 = *(const float4*)ap;
            float4 a1 = *(const float4*)(ap + 4);
            af[0] = f2bf(a0.x); af[1] = f2bf(a0.y); af[2] = f2bf(a0.z); af[3] = f2bf(a0.w);
            af[4] = f2bf(a1.x); af[5] = f2bf(a1.y); af[6] = f2bf(a1.z); af[7] = f2bf(a1.w);
        }
#pragma unroll
        for (int nt = 0; nt < 8; ++nt) {
            short8 bf = *(const short8*)(Wf + (size_t)((nt * 4 + kt) * 64 + lane) * 8);
            acc[nt] = __builtin_amdgcn_mfma_f32_16x16x32_bf16(af, bf, acc[nt], 0, 0, 0);
        }
    }
    // C/D layout: col = lane&15, row = quad*4 + reg   [measured m89/m91]
    float4 dv = *(const float4*)(dinv + rowbase + quad * 4);
    float dvv[4] = {dv.x, dv.y, dv.z, dv.w};
    int col = lane & 15;
#pragma unroll
    for (int r = 0; r < 4; ++r) {
        int orow = rowbase + quad * 4 + r;
        if (orow < NN2) {
#pragma unroll
            for (int nt = 0; nt < 8; ++nt)
                hp[(size_t)orow * FHID + nt * 16 + col] =
                    (unsigned short)f2bf(acc[nt][r] * dvv[r]);
        }
    }
}

// ------- Aggregate: 16 lanes/node, dwordx4 gathers, depth-2 x batch-4 pipeline
// with LDS-staged indices (r8/r11-validated, ~90us/dispatch — request-path
// floor; two maximally different schedules converge here).

#define SCHB __builtin_amdgcn_sched_barrier(0)
#define RDI(S, EE) { _Pragma("unroll") for (int j = 0; j < 4; ++j) S[j] = (int)sidx[(EE) + j]; }
#define GTH(V, S)  { _Pragma("unroll") for (int j = 0; j < 4; ++j) V[j] = hpg[(size_t)S[j] * 16 + l16]; }
#define ACC4(V)    { _Pragma("unroll") for (int j = 0; j < 4; ++j) { \
                       a0 += bfpair(V[j].x); a1 += bfpair(V[j].y);   \
                       a2 += bfpair(V[j].z); a3 += bfpair(V[j].w); } }

__global__ __launch_bounds__(256) void k_agg(const uint4* __restrict__ hp4,
                                             const int* __restrict__ off,
                                             const unsigned short* __restrict__ csrc,
                                             const float* __restrict__ dinv,
                                             const float* __restrict__ bias,
                                             const unsigned short* __restrict__ resid,
                                             unsigned short* __restrict__ hout) {
    __shared__ unsigned short sidx[MAXE_BLK + 16];
    int tid = threadIdx.x;
    int l16 = tid & 15;
    int grp = tid >> 4;                       // 16 node-groups per block
    int gnb = blockIdx.x * 16;                // 6250 blocks -> 100,000 nodes
    // stage the block's contiguous csrc range into LDS (coalesced)
    int blkBeg = off[gnb];
    int blkLen = off[gnb + 16] - blkBeg;      // off[NN2] valid (csroff has NN2+1)
    if (blkLen > MAXE_BLK) blkLen = MAXE_BLK; // 68-sigma impossible; fault-safe clamp
    for (int i = tid; i < blkLen; i += 256)
        sidx[i] = csrc[blkBeg + i];
    __syncthreads();

    int gn = gnb + grp;
    int g = gn >= NN;
    int node = gn - g * NN;
    const uint4* hpg = hp4 + (size_t)g * NN * 16;
    int beg = off[gn], end = off[gn + 1];
    int lbeg = beg - blkBeg;

    uint4 sv = hpg[(size_t)node * 16 + l16];  // self-loop row (oldest; used in epilogue)
    f32x2 a0 = (f32x2){0.f, 0.f}, a1 = (f32x2){0.f, 0.f};
    f32x2 a2 = (f32x2){0.f, 0.f}, a3 = (f32x2){0.f, 0.f};

    int n4 = (end - beg) >> 2;                // full 4-batches
    if (n4 >= 2) {
        int s0[4], s1[4];
        uint4 v0[4], v1[4];
        int e = lbeg;
        RDI(s0, e);
        RDI(s1, e + 4);
        GTH(v0, s0); SCHB;                    // batch 0 in flight
        e += 8;
        int k = 1;                            // next batch to issue
        while (k + 2 <= n4) {
            GTH(v1, s1); SCHB;                // issue batch k (v0+v1 in flight)
            RDI(s0, e); e += 4;               // LDS idx batch k+1 (lgkm, no vmcnt)
            ACC4(v0);                         // counted vmcnt; batch k stays in flight
            GTH(v0, s0); SCHB;                // issue batch k+1
            RDI(s1, e); e += 4;               // LDS idx batch k+2 (pad-safe)
            ACC4(v1);
            k += 2;
        }
        if (k < n4) {                         // one more full batch (k == n4-1)
            GTH(v1, s1); SCHB;
            ACC4(v0);
            ACC4(v1);
        } else {
            ACC4(v0);
        }
    } else if (n4 == 1) {
        int s0[4]; uint4 v0[4];
        RDI(s0, lbeg);
        GTH(v0, s0);
        ACC4(v0);
    }
    // tail (<4 edges) from LDS indices
    int et = lbeg + (n4 << 2), lend = lbeg + (end - beg);
    for (; et < lend; ++et) {
        uint4 w = hpg[(size_t)sidx[et] * 16 + l16];
        a0 += bfpair(w.x); a1 += bfpair(w.y); a2 += bfpair(w.z); a3 += bfpair(w.w);
    }
    // self-loop contribution (sv issued at kernel start)
    a0 += bfpair(sv.x); a1 += bfpair(sv.y); a2 += bfpair(sv.z); a3 += bfpair(sv.w);

    float dv = dinv[gn];
    float4 b0 = ((const float4*)bias)[l16 * 2];
    float4 b1 = ((const float4*)bias)[l16 * 2 + 1];
    float o0 = fmaxf(a0.x * dv + b0.x, 0.f);
    float o1 = fmaxf(a0.y * dv + b0.y, 0.f);
    float o2 = fmaxf(a1.x * dv + b0.z, 0.f);
    float o3 = fmaxf(a1.y * dv + b0.w, 0.f);
    float o4 = fmaxf(a2.x * dv + b1.x, 0.f);
    float o5 = fmaxf(a2.y * dv + b1.y, 0.f);
    float o6 = fmaxf(a3.x * dv + b1.z, 0.f);
    float o7 = fmaxf(a3.y * dv + b1.w, 0.f);
    if (resid) {
        uint4 rv = ((const uint4*)resid)[(size_t)gn * 16 + l16];
        o0 += bflo(rv.x); o1 += bfhi(rv.x);
        o2 += bflo(rv.y); o3 += bfhi(rv.y);
        o4 += bflo(rv.z); o5 += bfhi(rv.z);
        o6 += bflo(rv.w); o7 += bfhi(rv.w);
    }
    uint4 ov;
    ov.x = packbf(o0, o1);
    ov.y = packbf(o2, o3);
    ov.z = packbf(o4, o5);
    ov.w = packbf(o6, o7);
    ((uint4*)hout)[(size_t)gn * 16 + l16] = ov;
}

// ---------------- Pooling (r10 form: 1024 blocks — 2048 waves hide the
// scattered row reads; the 256-block fused variant measured -22us, reverted) ----

static __device__ __forceinline__ int lbound(const int* __restrict__ a, int key) {
    int lo = 0, hi = NN;
    while (lo < hi) { int mid = (lo + hi) >> 1; if (a[mid] < key) lo = mid + 1; else hi = mid; }
    return lo;
}

__global__ void k_pool(const unsigned short* __restrict__ h,
                       const int* __restrict__ b0, const int* __restrict__ b1,
                       float* __restrict__ pooled, float* __restrict__ stats) {
    int b = blockIdx.x;                  // 1024 blocks
    int g = b >> 9, lg = b & 511;
    int c = threadIdx.x;                 // 128 threads
    if (b == 0) {                        // idempotent with k_bhist's zeroing
        for (int i = c; i < 2048; i += 128) stats[i] = 0.f;
    }
    const int* batch = g ? b1 : b0;
    int beg = lbound(batch, lg);
    int end = lbound(batch, lg + 1);
    const unsigned short* hb = h + (size_t)g * NN * FHID;
    float s = 0.f;
    for (int i = beg; i < end; ++i) s += bf2f(hb[(size_t)i * FHID + c]);
    int cnt = end - beg;
    pooled[(size_t)b * FHID + c] = s / (float)(cnt > 0 ? cnt : 1);
}

// ---------------- Head GEMMs (1024 rows = both graphs) ----------------
// k_head<NC>: 256 blocks x 256 threads, 4 rows/block. Thread owns one output
// column (coalesced W[k][c] loads), K-loop unrolled x8, As staged in LDS,
// compile-time trip counts. statsIn applies BN input transform (bnRelu:
// relu(BN) vs BN); statsOut accumulates column sum/sumsq.

template<int NC>
__global__ __launch_bounds__(256) void k_head(const float* __restrict__ A,
                                              const float* __restrict__ W,
                                              const float* __restrict__ bias,
                                              float* __restrict__ out,
                                              int K, int act,
                                              float* __restrict__ statsOut,
                                              const float* __restrict__ statsIn,
                                              const float* __restrict__ gIn,
                                              const float* __restrict__ beIn,
                                              int bnRelu, float* __restrict__ zout) {
    constexpr int NGRP = 256 / NC;        // 1 (NC=256) or 2 (NC=128)
    constexpr int RPG  = 4 / NGRP;        // 4 or 2 rows per thread
    __shared__ float As[4 * 256];         // 4 rows x K (K <= 256)
    __shared__ float scl[256], shf[256];
    int t = threadIdx.x;
    int c = t & (NC - 1);
    int rg = t / NC;                      // 0 .. NGRP-1
    int r0 = blockIdx.x * 4;              // 256 blocks -> 1024 rows
    int g = (r0 >= NG) ? 1 : 0;
    if (statsIn) {
        const float* si = statsIn + g * 512;
        for (int j = t; j < K; j += 256) {
            float m = si[j] * (1.f / 512.f);
            float var = si[K + j] * (1.f / 512.f) - m * m;
            float inv = 1.0f / sqrtf(var + 1e-5f);
            float s = gIn[j] * inv;
            scl[j] = s;
            shf[j] = beIn[j] - m * s;
        }
    }
    __syncthreads();
    for (int idx = t; idx < 4 * K; idx += 256) {
        float v = A[(size_t)r0 * K + idx];
        if (statsIn) {
            int k = idx & (K - 1);        // K is 128 or 256
            v = v * scl[k] + shf[k];
            if (bnRelu) v = fmaxf(v, 0.f);
        }
        if (zout) zout[(size_t)r0 * K + idx] = v;
        As[idx] = v;
    }
    __syncthreads();
    float bb = bias[c];
    float acc[RPG];
#pragma unroll
    for (int r = 0; r < RPG; ++r) acc[r] = bb;
    const float* Ab = As + (rg * RPG) * K;
    for (int k = 0; k < K; k += 8) {      // K % 8 == 0
        float w0 = W[(size_t)(k + 0) * NC + c];
        float w1 = W[(size_t)(k + 1) * NC + c];
        float w2 = W[(size_t)(k + 2) * NC + c];
        float w3 = W[(size_t)(k + 3) * NC + c];
        float w4 = W[(size_t)(k + 4) * NC + c];
        float w5 = W[(size_t)(k + 5) * NC + c];
        float w6 = W[(size_t)(k + 6) * NC + c];
        float w7 = W[(size_t)(k + 7) * NC + c];
#pragma unroll
        for (int r = 0; r < RPG; ++r) {
            float4 a0 = *(const float4*)(Ab + r * K + k);
            float4 a1 = *(const float4*)(Ab + r * K + k + 4);
            acc[r] = fmaf(a0.x, w0, acc[r]);
            acc[r] = fmaf(a0.y, w1, acc[r]);
            acc[r] = fmaf(a0.z, w2, acc[r]);
            acc[r] = fmaf(a0.w, w3, acc[r]);
            acc[r] = fmaf(a1.x, w4, acc[r]);
            acc[r] = fmaf(a1.y, w5, acc[r]);
            acc[r] = fmaf(a1.z, w6, acc[r]);
            acc[r] = fmaf(a1.w, w7, acc[r]);
        }
    }
    if (statsOut) {                       // used only by NC=256 heads
        float s = 0.f, q = 0.f;
#pragma unroll
        for (int r = 0; r < RPG; ++r) { s += acc[r]; q += acc[r] * acc[r]; }
        atomicAdd(&statsOut[g * 512 + c], s);
        atomicAdd(&statsOut[g * 512 + NC + c], q);
    }
#pragma unroll
    for (int r = 0; r < RPG; ++r) {
        float v = acc[r];
        if (act) v = fmaxf(v, 0.f);
        out[(size_t)(r0 + rg * RPG + r) * NC + c] = v;
    }
}

// ---------------- Fused predictor (head3+head4): block b owns rows 4b..4b+3
// end-to-end. z = BN(t2) -> z_out; t3 = relu(z@Wq1+bq1) stays in LDS;
// p = t3@Wq2+bq2 -> p_out. Removes the t3 global round-trip + one dispatch.

__global__ __launch_bounds__(256) void k_head34(const float* __restrict__ A,    // t2
                                                const float* __restrict__ W1,   // Wq1 256x128
                                                const float* __restrict__ bq1,
                                                const float* __restrict__ W2,   // Wq2 128x256
                                                const float* __restrict__ bq2,
                                                const float* __restrict__ statsIn, // st2
                                                const float* __restrict__ gIn,
                                                const float* __restrict__ beIn,
                                                float* __restrict__ zout,
                                                float* __restrict__ pout) {
    __shared__ float As[4 * 256];
    __shared__ float Bs[4 * 128];
    __shared__ float scl[256], shf[256];
    int t = threadIdx.x;
    int r0 = blockIdx.x * 4;              // 256 blocks -> 1024 rows
    int g = (r0 >= NG) ? 1 : 0;
    {
        const float* si = statsIn + g * 512;
        float m = si[t] * (1.f / 512.f);
        float var = si[256 + t] * (1.f / 512.f) - m * m;
        float inv = 1.0f / sqrtf(var + 1e-5f);
        float s = gIn[t] * inv;
        scl[t] = s;
        shf[t] = beIn[t] - m * s;
    }
    __syncthreads();
    for (int idx = t; idx < 4 * 256; idx += 256) {
        int k = idx & 255;
        float v = A[(size_t)r0 * 256 + idx] * scl[k] + shf[k];   // BN, no relu
        zout[(size_t)r0 * 256 + idx] = v;
        As[idx] = v;
    }
    __syncthreads();
    // GEMM1: K=256 -> 128 cols, relu, into LDS Bs (2 rows per thread)
    {
        int c = t & 127, rg = t >> 7;
        float bb = bq1[c];
        float a0 = bb, a1 = bb;
        const float* Ab = As + (rg * 2) * 256;
        for (int k = 0; k < 256; k += 8) {
            float w0 = W1[(size_t)(k + 0) * 128 + c];
            float w1 = W1[(size_t)(k + 1) * 128 + c];
            float w2 = W1[(size_t)(k + 2) * 128 + c];
            float w3 = W1[(size_t)(k + 3) * 128 + c];
            float w4 = W1[(size_t)(k + 4) * 128 + c];
            float w5 = W1[(size_t)(k + 5) * 128 + c];
            float w6 = W1[(size_t)(k + 6) * 128 + c];
            float w7 = W1[(size_t)(k + 7) * 128 + c];
            float4 q0 = *(const float4*)(Ab + k);
            float4 q1 = *(const float4*)(Ab + k + 4);
            float4 p0 = *(const float4*)(Ab + 256 + k);
            float4 p1 = *(const float4*)(Ab + 256 + k + 4);
            a0 = fmaf(q0.x, w0, a0); a1 = fmaf(p0.x, w0, a1);
            a0 = fmaf(q0.y, w1, a0); a1 = fmaf(p0.y, w1, a1);
            a0 = fmaf(q0.z, w2, a0); a1 = fmaf(p0.z, w2, a1);
            a0 = fmaf(q0.w, w3, a0); a1 = fmaf(p0.w, w3, a1);
            a0 = fmaf(q1.x, w4, a0); a1 = fmaf(p1.x, w4, a1);
            a0 = fmaf(q1.y, w5, a0); a1 = fmaf(p1.y, w5, a1);
            a0 = fmaf(q1.z, w6, a0); a1 = fmaf(p1.z, w6, a1);
            a0 = fmaf(q1.w, w7, a0); a1 = fmaf(p1.w, w7, a1);
        }
        Bs[(rg * 2 + 0) * 128 + c] = fmaxf(a0, 0.f);
        Bs[(rg * 2 + 1) * 128 + c] = fmaxf(a1, 0.f);
    }
    __syncthreads();
    // GEMM2: K=128 -> 256 cols (4 rows per thread)
    {
        float bb = bq2[t];
        float acc[4] = {bb, bb, bb, bb};
        for (int k = 0; k < 128; k += 8) {
            float w0 = W2[(size_t)(k + 0) * 256 + t];
            float w1 = W2[(size_t)(k + 1) * 256 + t];
            float w2 = W2[(size_t)(k + 2) * 256 + t];
            float w3 = W2[(size_t)(k + 3) * 256 + t];
            float w4 = W2[(size_t)(k + 4) * 256 + t];
            float w5 = W2[(size_t)(k + 5) * 256 + t];
            float w6 = W2[(size_t)(k + 6) * 256 + t];
            float w7 = W2[(size_t)(k + 7) * 256 + t];
#pragma unroll
            for (int r = 0; r < 4; ++r) {
                float4 q0 = *(const float4*)(Bs + r * 128 + k);
                float4 q1 = *(const float4*)(Bs + r * 128 + k + 4);
                acc[r] = fmaf(q0.x, w0, acc[r]);
                acc[r] = fmaf(q0.y, w1, acc[r]);
                acc[r] = fmaf(q0.z, w2, acc[r]);
                acc[r] = fmaf(q0.w, w3, acc[r]);
                acc[r] = fmaf(q1.x, w4, acc[r]);
                acc[r] = fmaf(q1.y, w5, acc[r]);
                acc[r] = fmaf(q1.z, w6, acc[r]);
                acc[r] = fmaf(q1.w, w7, acc[r]);
            }
        }
#pragma unroll
        for (int r = 0; r < 4; ++r)
            pout[(size_t)(r0 + r) * 256 + t] = acc[r];
    }
}

// ---------------- Orchestration ----------------

extern "C" void kernel_launch(void* const* d_in, const int* in_sizes, int n_in,
                              void* d_out, int out_size, void* d_ws, size_t ws_size,
                              hipStream_t stream) {
    const float* x1 = (const float*)d_in[0];
    const float* x2 = (const float*)d_in[3];
    const int*   ei[2]    = {(const int*)d_in[1], (const int*)d_in[4]};
    const int*   batch[2] = {(const int*)d_in[2], (const int*)d_in[5]};
    const float* W[3]  = {(const float*)d_in[6], (const float*)d_in[8], (const float*)d_in[10]};
    const float* bb[3] = {(const float*)d_in[7], (const float*)d_in[9], (const float*)d_in[11]};
    const float* Wp1 = (const float*)d_in[12]; const float* bp1 = (const float*)d_in[13];
    const float* g1  = (const float*)d_in[14]; const float* be1 = (const float*)d_in[15];
    const float* Wp2 = (const float*)d_in[16]; const float* bp2 = (const float*)d_in[17];
    const float* g2  = (const float*)d_in[18]; const float* be2 = (const float*)d_in[19];
    const float* Wq1 = (const float*)d_in[20]; const float* bq1 = (const float*)d_in[21];
    const float* Wq2 = (const float*)d_in[22]; const float* bq2 = (const float*)d_in[23];

    char* ws = (char*)d_ws;
    size_t off = 0;
    auto alloc = [&](size_t bytes) -> void* {
        void* p = ws + off;
        off += (bytes + 255) & ~(size_t)255;
        return p;
    };
    unsigned short* h_cur  = (unsigned short*)alloc((size_t)NN2 * FHID * 2);  // bf16 state
    unsigned short* hp     = (unsigned short*)alloc((size_t)NN2 * FHID * 2);  // bf16 pre-agg
    unsigned short* csrc   = (unsigned short*)alloc((size_t)(NE2 + 16) * 2);  // +16 pad
    int*            csroff = (int*)alloc((size_t)(NN2 + 1) * 4);
    unsigned short* lrank  = (unsigned short*)alloc((size_t)NE2 * 2);
    unsigned*       pedge  = (unsigned*)alloc((size_t)NE2 * 4);
    int*            histG  = (int*)alloc((size_t)NHIST2 * 4);
    int*            histS  = (int*)alloc((size_t)NHIST2 * 4);
    int*            bsum   = (int*)alloc(512 * 4);
    float*          dinv   = (float*)alloc((size_t)100352 * 4);  // padded for gemm epilogue
    float*          pooled = (float*)alloc((size_t)2 * NG * FHID * 4);
    short*          Wf     = (short*)alloc((size_t)3 * 16384 * 2);
    float*          t1     = (float*)alloc((size_t)1024 * 256 * 4);
    float*          t2     = (float*)alloc((size_t)1024 * 256 * 4);
    float*          stats  = (float*)alloc(2048 * 4);  // [st1: 2g x 512][st2: 2g x 512]

    const int* src0 = ei[0];           const int* dst0 = ei[0] + NEDGE;
    const int* src1 = ei[1];           const int* dst1 = ei[1] + NEDGE;

    // merged atomic-free radix CSR build + fused weight prep + stats zero
    k_bhist<<<NABLK2 + 6, 1024, 0, stream>>>(dst0, dst1, histG, lrank,
                                             W[0], W[1], W[2], Wf, stats);
    s_scan256<<<NSB1, 256, 0, stream>>>(histG, histS, bsum, NHIST2);
    s_scan_tail<<<1, 512, 0, stream>>>(bsum, NSB1);
    k_part<<<NABLK2, 1024, 0, stream>>>(src0, dst0, src1, dst1, lrank, histS,
                                        bsum, pedge);
    k_csr<<<NBUCK2, 512, 0, stream>>>(pedge, histS, bsum, csroff, csrc, dinv);

    // encoder: merged gemm, merged two-graph aggregation (LDS-idx pipelined gathers)
    for (int l = 0; l < 3; ++l) {
        const unsigned short* Abf = (l == 0) ? nullptr : h_cur;
        const unsigned short* resid = (l == 0) ? nullptr : h_cur;
        k_gemm<<<1564, 256, 0, stream>>>(x1, x2, Abf, Wf + (size_t)l * 16384, dinv, hp);
        k_agg<<<6250, 256, 0, stream>>>((const uint4*)hp, csroff, csrc, dinv,
                                        bb[l], resid, h_cur);
    }
    k_pool<<<1024, 128, 0, stream>>>(h_cur, batch[0], batch[1], pooled, stats);

    // heads: h1 (stats st1), h2 (BN(st1)+relu -> stats st2), fused h3+h4
    float* outp = (float*)d_out;
    float* p_out = outp;                           // p1,p2 contiguous [1024,256]
    float* z_out = outp + (size_t)2 * NG * FPROJ;  // z1,z2 contiguous [1024,256]
    float* st1 = stats, *st2 = stats + 1024;
    k_head<256><<<256, 256, 0, stream>>>(pooled, Wp1, bp1, t1, 128, 0,
                                         st1, nullptr, nullptr, nullptr, 0, nullptr);
    k_head<256><<<256, 256, 0, stream>>>(t1, Wp2, bp2, t2, 256, 0,
                                         st2, st1, g1, be1, 1, nullptr);
    k_head34<<<256, 256, 0, stream>>>(t2, Wq1, bq1, Wq2, bq2,
                                      st2, g2, be2, z_out, p_out);
}